// Round 7
// baseline (139.943 us; speedup 1.0000x reference)
//
#include <hip/hip_runtime.h>
#include <hip/hip_cooperative_groups.h>

namespace cg = cooperative_groups;

#define B 16
#define CIN 4
#define COUT 8
#define KW 5
#define S 2048
#define BS (B * S)
#define NW (COUT * CIN * KW)   // 160 weights per conv

typedef _Float16 f16;
typedef _Float16 f16x4 __attribute__((ext_vector_type(4)));
typedef _Float16 f16x8 __attribute__((ext_vector_type(8)));
typedef __fp16 fp16x2 __attribute__((ext_vector_type(2)));
typedef float f32x16 __attribute__((ext_vector_type(16)));

#define QT 32
#define NWAVE 4
#define KVC (S / NWAVE)   // 512 kv per wave

// ---------------------------------------------------------------------------
// Fused kernel, cooperative launch, grid = 1024 blocks x 256 threads
// (= 4 blocks/CU co-resident; __launch_bounds__(256,4) caps VGPR at 128).
//
// Phase 1 (blocks 0..383): three causal reflect-padded convs.
//   part 0: qe = conv(q, wq) * QSCALE -> [b][s][8] f16   (exp2-domain scale)
//   part 1: ke = conv(v, wk)          -> [b][s][8] f16   (swapped wiring!)
//   part 2: ve = conv(k, wv)          -> vt [b][n][s] f16 (TRANSPOSED)
// grid.sync()  (device-scope fence -> cross-XCD visibility)
// Phase 2 (all blocks): flash attention via v_mfma_f32_32x32x16_f16.
//
// SPLIT-K fragment layout (gfx950 = two stacked legacy 32x32x8 fragments):
//   A[m][k], B[k][n]: lane l elem j <-> k = (l>>5)*4 + (j&3) + 8*(j>>2)
//   C/D: col = lane&31, row = (r&3) + 8*(r>>2) + 4*(lane>>5)
// QK^T swapped: C[kv][q] = mfma(A=K[32kv x 16dpad], B=Q^T[16dpad x 32q]);
// p = exp2(C) feeds PV's B fragment DIRECTLY (owned C-rows == needed k-idx).
// PV: C[n][q] += mfma(A=V^T[32n x 16kv], B=P) x2; lane row n==8 uses a
// constant-1 A-frag so C row 8 accumulates the softmax denominator l.
// Epilogue: LDS-reduce 4 waves, normalize, 8x8 linear + bias, store.
// ---------------------------------------------------------------------------
__global__ __launch_bounds__(256, 4) void fused_attn_kernel(
    const float* __restrict__ q, const float* __restrict__ kin,
    const float* __restrict__ v, const float* __restrict__ wq,
    const float* __restrict__ wk, const float* __restrict__ wv,
    const float* __restrict__ w_out, const float* __restrict__ b_out,
    f16* __restrict__ qe, f16* __restrict__ ke, f16* __restrict__ vt,
    float* __restrict__ out)
{
    __shared__ float smem[NWAVE * 9 * QT];   // 1152 floats; conv uses first 160
    int tid = threadIdx.x;

    // ================= Phase 1: conv (blocks 0..383) =================
    if (blockIdx.x < 384) {
        int part = blockIdx.x >> 7;          // 0,1,2
        int blk  = blockIdx.x & 127;
        const float* in; const float* wsrc;
        if (part == 0)      { in = q;   wsrc = wq; }
        else if (part == 1) { in = v;   wsrc = wk; }   // ke = conv(v, wk)
        else                { in = kin; wsrc = wv; }   // ve = conv(k, wv)

        if (tid < NW) smem[tid] = wsrc[tid];
        __syncthreads();

        int gid = blk * 256 + tid;           // b*S + s
        int s = gid & (S - 1);
        int b = gid >> 11;

        float x[CIN][KW];
#pragma unroll
        for (int c = 0; c < CIN; ++c) {
            const float* ip = in + ((size_t)(b * CIN + c) << 11);
#pragma unroll
            for (int i = 0; i < KW; ++i) {
                int idx = s + i - 4;
                idx = idx < 0 ? -idx : idx;  // reflect pad
                x[c][i] = ip[idx];
            }
        }

        float o[COUT];
#pragma unroll
        for (int oc = 0; oc < COUT; ++oc) {
            float a = 0.f;
#pragma unroll
            for (int c = 0; c < CIN; ++c)
#pragma unroll
                for (int i = 0; i < KW; ++i)
                    a += x[c][i] * smem[(oc * CIN + c) * KW + i];
            o[oc] = a;
        }

        const float QSCALE = 0.35355339059327373f * 1.4426950408889634f;

        if (part == 2) {
#pragma unroll
            for (int oc = 0; oc < COUT; ++oc)
                vt[((size_t)(b * COUT + oc) << 11) + s] = (f16)o[oc];
        } else {
            float sc = (part == 0) ? QSCALE : 1.0f;
            f16x8 r;
#pragma unroll
            for (int j = 0; j < 8; ++j) r[j] = (f16)(o[j] * sc);
            f16* dst = ((part == 0) ? qe : ke) + ((size_t)gid << 3);
            *(f16x8*)dst = r;
        }
    }

    cg::this_grid().sync();   // all conv outputs visible device-wide

    // ================= Phase 2: MFMA flash attention =================
    float (*red)[9][QT] = (float(*)[9][QT])smem;

    int w    = tid >> 6;
    int lane = tid & 63;
    int hi   = lane >> 5;
    int ln   = lane & 31;

    int b  = blockIdx.x >> 6;      // 64 q-tiles per batch
    int q0 = (blockIdx.x & 63) * QT;

    // Q fragment (B operand): elems 0..3 = Q[q0+ln][4*hi .. 4*hi+3]
    f16x4 qh = *(const f16x4*)(qe + ((size_t)(b * S + q0 + ln) << 3) + hi * 4);
    f16x8 qb = {qh[0], qh[1], qh[2], qh[3], (f16)0, (f16)0, (f16)0, (f16)0};

    f32x16 oacc = {};              // C[n][q]; row n=8 accumulates l

    int kv0 = w * KVC;
    for (int it = 0; it < KVC / 32; ++it, kv0 += 32) {
        // ---- QK^T ----
        f16x4 kh = *(const f16x4*)(ke + ((size_t)(b * S + kv0 + ln) << 3) + hi * 4);
        f16x8 ka = {kh[0], kh[1], kh[2], kh[3], (f16)0, (f16)0, (f16)0, (f16)0};
        f32x16 sc = {};
        sc = __builtin_amdgcn_mfma_f32_32x32x16_f16(ka, qb, sc, 0, 0, 0);

        // ---- exp2 (pre-scaled scores; no max tracking needed) ----
        float p[16];
#pragma unroll
        for (int r = 0; r < 16; ++r) p[r] = __builtin_amdgcn_exp2f(sc[r]);

        // ---- pack to f16; owned C-rows == needed B-frag k-indices ----
        union { f16x8 v; fp16x2 h[4]; } p1, p2;
#pragma unroll
        for (int i = 0; i < 4; ++i) {
            p1.h[i] = __builtin_amdgcn_cvt_pkrtz(p[2 * i],     p[2 * i + 1]);
            p2.h[i] = __builtin_amdgcn_cvt_pkrtz(p[8 + 2 * i], p[8 + 2 * i + 1]);
        }

        // ---- V^T A-fragments (split-k halves) ----
        f16x8 va1, va2;
        if (ln < COUT) {
            const f16* vr = vt + ((size_t)(b * COUT + ln) << 11) + kv0;
            f16x4 a0 = *(const f16x4*)(vr + hi * 4);
            f16x4 a1 = *(const f16x4*)(vr + 8 + hi * 4);
            f16x4 a2 = *(const f16x4*)(vr + 16 + hi * 4);
            f16x4 a3 = *(const f16x4*)(vr + 24 + hi * 4);
            va1 = (f16x8){a0[0], a0[1], a0[2], a0[3], a1[0], a1[1], a1[2], a1[3]};
            va2 = (f16x8){a2[0], a2[1], a2[2], a2[3], a3[0], a3[1], a3[2], a3[3]};
        } else if (ln == COUT) {
            f16 one = (f16)1.0f;
            va1 = (f16x8){one, one, one, one, one, one, one, one};
            va2 = va1;
        } else {
            va1 = (f16x8){};
            va2 = (f16x8){};
        }

        oacc = __builtin_amdgcn_mfma_f32_32x32x16_f16(va1, p1.v, oacc, 0, 0, 0);
        oacc = __builtin_amdgcn_mfma_f32_32x32x16_f16(va2, p2.v, oacc, 0, 0, 0);
    }

    // ---- epilogue ----
#pragma unroll
    for (int r = 0; r < 16; ++r) {
        int n = (r & 3) + 8 * (r >> 2) + 4 * hi;
        if (n < 9) red[w][n][ln] = oacc[r];
    }
    __syncthreads();

    if (tid < 32)                  // row 8 = denominator l
        red[0][8][tid] = red[0][8][tid] + red[1][8][tid] + red[2][8][tid] + red[3][8][tid];
    {
        int n = tid >> 5, qq = tid & 31;   // rows 0..7
        red[0][n][qq] = red[0][n][qq] + red[1][n][qq] + red[2][n][qq] + red[3][n][qq];
    }
    __syncthreads();

    {
        int cp = tid >> 5, qq = tid & 31;   // 8 channels x 32 q
        float inv = 1.0f / red[0][8][qq];
        float y = b_out[cp];
#pragma unroll
        for (int c = 0; c < 8; ++c) y += w_out[cp * 8 + c] * red[0][c][qq] * inv;
        out[(((size_t)(b * COUT + cp)) << 11) + q0 + qq] = y;
    }
}

// ---------------------------------------------------------------------------
extern "C" void kernel_launch(void* const* d_in, const int* in_sizes, int n_in,
                              void* d_out, int out_size, void* d_ws, size_t ws_size,
                              hipStream_t stream)
{
    const float* q     = (const float*)d_in[0];
    const float* k     = (const float*)d_in[1];
    const float* v     = (const float*)d_in[2];
    const float* wq    = (const float*)d_in[3];
    const float* wk    = (const float*)d_in[4];
    const float* wv    = (const float*)d_in[5];
    const float* w_out = (const float*)d_in[6];
    const float* b_out = (const float*)d_in[7];
    float* out = (float*)d_out;

    f16* qe = (f16*)d_ws;                        // [B][S][8]
    f16* ke = qe + (size_t)BS * COUT;            // [B][S][8]
    f16* vt = ke + (size_t)BS * COUT;            // [B][8][S]

    void* args[] = {(void*)&q, (void*)&k, (void*)&v, (void*)&wq, (void*)&wk,
                    (void*)&wv, (void*)&w_out, (void*)&b_out,
                    (void*)&qe, (void*)&ke, (void*)&vt, (void*)&out};

    hipLaunchCooperativeKernel((const void*)fused_attn_kernel,
                               dim3(B * (S / QT)), dim3(256), args, 0, stream);
}

// Round 9
// 41.628 us; speedup vs baseline: 3.3618x; 3.3618x over previous
//
#include <hip/hip_runtime.h>

#define B 16
#define CIN 4
#define COUT 8
#define KW 5
#define S 2048
#define BS (B * S)
#define NW (COUT * CIN * KW)   // 160 weights per conv

typedef _Float16 f16;
typedef _Float16 f16x4 __attribute__((ext_vector_type(4)));
typedef _Float16 f16x8 __attribute__((ext_vector_type(8)));
typedef __fp16 fp16x2 __attribute__((ext_vector_type(2)));
typedef float f32x16 __attribute__((ext_vector_type(16)));

// ---------------------------------------------------------------------------
// Kernel 1: three causal (reflect-padded) convs, LDS-staged, 6-way split:
// grid = 768 blocks = 3 parts x 2 oc-halves x 128 position-blocks (3/CU).
// part 0: qe = conv(q, wq) * QSCALE -> [b][s][8] f16  (exp2-domain scale)
// part 1: ke = conv(v, wk)          -> [b][s][8] f16  (swapped wiring!)
// part 2: ve = conv(k, wv)          -> vt [b][n][s] f16 (TRANSPOSED)
// Block stages taps [s0-4 .. s0+259] x 4 cin in LDS (strided loop covers all
// 264 entries with 256 threads — R8 bug was `if(tid<264)` leaving 256..263
// uninitialized). Each thread computes 4 output channels.
// ---------------------------------------------------------------------------
__global__ __launch_bounds__(256) void conv_embed_kernel(
    const float* __restrict__ q, const float* __restrict__ k,
    const float* __restrict__ v, const float* __restrict__ wq,
    const float* __restrict__ wk, const float* __restrict__ wv,
    f16* __restrict__ qe, f16* __restrict__ ke, f16* __restrict__ vt)
{
    __shared__ float xs[CIN][264];
    __shared__ float wsm[80];

    int tid  = threadIdx.x;
    int blk  = blockIdx.x & 127;   // position block: b = blk>>3, s0 = (blk&7)*256
    int grp  = blockIdx.x >> 7;    // 0..5
    int part = grp >> 1;           // 0,1,2
    int oh   = grp & 1;            // oc half

    const float* in; const float* wsrc;
    if (part == 0)      { in = q; wsrc = wq; }
    else if (part == 1) { in = v; wsrc = wk; }   // ke = conv(v, wk)
    else                { in = k; wsrc = wv; }   // ve = conv(k, wv)

    if (tid < 80) wsm[tid] = wsrc[oh * 80 + tid];

    int b  = blk >> 3;
    int s0 = (blk & 7) * 256;

    // Stage taps [s0-4, s0+259] for 4 input channels; reflect left, clamp right
    // (clamped entries are never read as taps).
    for (int j = tid; j < 264; j += 256) {
        int idx = s0 - 4 + j;
        idx = idx < 0 ? -idx : idx;
        idx = idx > S - 1 ? S - 1 : idx;
#pragma unroll
        for (int c = 0; c < CIN; ++c)
            xs[c][j] = in[((size_t)(b * CIN + c) << 11) + idx];
    }
    __syncthreads();

    int s = s0 + tid;
    float x[CIN][KW];
#pragma unroll
    for (int c = 0; c < CIN; ++c)
#pragma unroll
        for (int i = 0; i < KW; ++i)
            x[c][i] = xs[c][tid + i];

    float o[4];
#pragma unroll
    for (int oo = 0; oo < 4; ++oo) {
        float a = 0.f;
#pragma unroll
        for (int c = 0; c < CIN; ++c)
#pragma unroll
            for (int i = 0; i < KW; ++i)
                a += x[c][i] * wsm[oo * 20 + c * 5 + i];
        o[oo] = a;
    }

    const float QSCALE = 0.35355339059327373f * 1.4426950408889634f; // (1/sqrt8)*log2e

    if (part == 2) {
#pragma unroll
        for (int oo = 0; oo < 4; ++oo)
            vt[((size_t)(b * COUT + oh * 4 + oo) << 11) + s] = (f16)o[oo];
    } else {
        float sc = (part == 0) ? QSCALE : 1.0f;
        f16x4 r;
#pragma unroll
        for (int oo = 0; oo < 4; ++oo) r[oo] = (f16)(o[oo] * sc);
        f16* dst = ((part == 0) ? qe : ke) + ((size_t)(b * S + s) << 3) + oh * 4;
        *(f16x4*)dst = r;
    }
}

// ---------------------------------------------------------------------------
// Kernel 2: flash attention via v_mfma_f32_32x32x16_f16, 1-tile software
// pipeline (next K/V fragments issued before the exp chain hides under
// TRANS work). V loads unconditional (row ln&7) + select, no divergence.
//
// SPLIT-K fragment layout (gfx950 = two stacked legacy 32x32x8 fragments):
//   A[m][k], B[k][n]: lane l elem j <-> k = (l>>5)*4 + (j&3) + 8*(j>>2)
//   C/D: col = lane&31, row = (r&3) + 8*(r>>2) + 4*(lane>>5)
// QK^T swapped: C[kv][q] = mfma(A=K, B=Q^T); p = exp2(C) feeds PV's B
// fragment DIRECTLY. PV: C[n][q] += mfma(A=V^T, B=P) x2; lane row n==8 uses
// constant-1 A-frag -> row 8 accumulates denominator l.
// ---------------------------------------------------------------------------
#define QT 32
#define NWAVE 4
#define KVC (S / NWAVE)   // 512 kv per wave

__global__ __launch_bounds__(256, 4) void attn_mfma_kernel(
    const f16* __restrict__ qe, const f16* __restrict__ ke,
    const f16* __restrict__ vt, const float* __restrict__ w_out,
    const float* __restrict__ b_out, float* __restrict__ out)
{
    __shared__ float red[NWAVE][9][QT];

    int tid  = threadIdx.x;
    int w    = tid >> 6;
    int lane = tid & 63;
    int hi   = lane >> 5;
    int ln   = lane & 31;

    int b  = blockIdx.x >> 6;      // 64 q-tiles per batch
    int q0 = (blockIdx.x & 63) * QT;

    // Q fragment (B operand): elems 0..3 = Q[q0+ln][4*hi .. 4*hi+3]
    f16x4 qh = *(const f16x4*)(qe + ((size_t)(b * S + q0 + ln) << 3) + hi * 4);
    f16x8 qb = {qh[0], qh[1], qh[2], qh[3], (f16)0, (f16)0, (f16)0, (f16)0};

    const f16* kbase = ke + ((size_t)(b * S) << 3) + hi * 4;                // + (kv+ln)*8
    const f16* vbase = vt + ((size_t)(b * COUT + (ln & 7)) << 11) + hi * 4; // + kv

    f32x16 oacc = {};              // C[n][q]; row n=8 accumulates l

    int kv = w * KVC;
    // ---- pipeline prologue: tile 0 fragments ----
    f16x4 kh = *(const f16x4*)(kbase + ((size_t)(kv + ln) << 3));
    f16x4 a0 = *(const f16x4*)(vbase + kv);
    f16x4 a1 = *(const f16x4*)(vbase + kv + 8);
    f16x4 a2 = *(const f16x4*)(vbase + kv + 16);
    f16x4 a3 = *(const f16x4*)(vbase + kv + 24);

    for (int it = 0; it < KVC / 32; ++it) {
        // ---- assemble current-tile operands from prefetched regs ----
        f16x8 ka  = {kh[0], kh[1], kh[2], kh[3], (f16)0, (f16)0, (f16)0, (f16)0};
        f16x8 va1 = {a0[0], a0[1], a0[2], a0[3], a1[0], a1[1], a1[2], a1[3]};
        f16x8 va2 = {a2[0], a2[1], a2[2], a2[3], a3[0], a3[1], a3[2], a3[3]};
        if (ln == COUT) {
            f16 one = (f16)1.0f;
            va1 = (f16x8){one, one, one, one, one, one, one, one};
            va2 = va1;
        } else if (ln > COUT) {
            va1 = (f16x8){};
            va2 = (f16x8){};
        }

        // ---- prefetch next tile (wraps harmlessly on last iter) ----
        int kvn = (it == KVC / 32 - 1) ? w * KVC : kv + 32;
        kh = *(const f16x4*)(kbase + ((size_t)(kvn + ln) << 3));
        a0 = *(const f16x4*)(vbase + kvn);
        a1 = *(const f16x4*)(vbase + kvn + 8);
        a2 = *(const f16x4*)(vbase + kvn + 16);
        a3 = *(const f16x4*)(vbase + kvn + 24);

        // ---- QK^T ----
        f32x16 sc = {};
        sc = __builtin_amdgcn_mfma_f32_32x32x16_f16(ka, qb, sc, 0, 0, 0);

        // ---- exp2 (pre-scaled scores; no max tracking) ----
        float p[16];
#pragma unroll
        for (int r = 0; r < 16; ++r) p[r] = __builtin_amdgcn_exp2f(sc[r]);

        // ---- pack to f16; owned C-rows == needed B-frag k-indices ----
        union { f16x8 v; fp16x2 h[4]; } p1, p2;
#pragma unroll
        for (int i = 0; i < 4; ++i) {
            p1.h[i] = __builtin_amdgcn_cvt_pkrtz(p[2 * i],     p[2 * i + 1]);
            p2.h[i] = __builtin_amdgcn_cvt_pkrtz(p[8 + 2 * i], p[8 + 2 * i + 1]);
        }

        // ---- PV ----
        oacc = __builtin_amdgcn_mfma_f32_32x32x16_f16(va1, p1.v, oacc, 0, 0, 0);
        oacc = __builtin_amdgcn_mfma_f32_32x32x16_f16(va2, p2.v, oacc, 0, 0, 0);

        kv += 32;
    }

    // ---- epilogue: dump useful C rows (n<9) to LDS ----
#pragma unroll
    for (int r = 0; r < 16; ++r) {
        int n = (r & 3) + 8 * (r >> 2) + 4 * hi;
        if (n < 9) red[w][n][ln] = oacc[r];
    }
    __syncthreads();

    if (tid < 32)                  // row 8 = denominator l
        red[0][8][tid] = red[0][8][tid] + red[1][8][tid] + red[2][8][tid] + red[3][8][tid];
    {
        int n = tid >> 5, qq = tid & 31;   // rows 0..7
        red[0][n][qq] = red[0][n][qq] + red[1][n][qq] + red[2][n][qq] + red[3][n][qq];
    }
    __syncthreads();

    {
        int cp = tid >> 5, qq = tid & 31;   // 8 channels x 32 q
        float inv = 1.0f / red[0][8][qq];
        float y = b_out[cp];
#pragma unroll
        for (int c = 0; c < 8; ++c) y += w_out[cp * 8 + c] * red[0][c][qq] * inv;
        out[(((size_t)(b * COUT + cp)) << 11) + q0 + qq] = y;
    }
}

// ---------------------------------------------------------------------------
extern "C" void kernel_launch(void* const* d_in, const int* in_sizes, int n_in,
                              void* d_out, int out_size, void* d_ws, size_t ws_size,
                              hipStream_t stream)
{
    const float* q     = (const float*)d_in[0];
    const float* k     = (const float*)d_in[1];
    const float* v     = (const float*)d_in[2];
    const float* wq    = (const float*)d_in[3];
    const float* wk    = (const float*)d_in[4];
    const float* wv    = (const float*)d_in[5];
    const float* w_out = (const float*)d_in[6];
    const float* b_out = (const float*)d_in[7];
    float* out = (float*)d_out;

    f16* qe = (f16*)d_ws;                        // [B][S][8]
    f16* ke = qe + (size_t)BS * COUT;            // [B][S][8]
    f16* vt = ke + (size_t)BS * COUT;            // [B][8][S]

    conv_embed_kernel<<<768, 256, 0, stream>>>(q, k, v, wq, wk, wv, qe, ke, vt);
    attn_mfma_kernel<<<B * (S / QT), 256, 0, stream>>>(qe, ke, vt, w_out, b_out, out);
}

// Round 10
// 26.708 us; speedup vs baseline: 5.2398x; 1.5586x over previous
//
#include <hip/hip_runtime.h>

#define B 16
#define CIN 4
#define COUT 8
#define KW 5
#define S 2048
#define BS (B * S)
#define NW (COUT * CIN * KW)   // 160 weights per conv

typedef _Float16 f16;
typedef _Float16 f16x4 __attribute__((ext_vector_type(4)));
typedef _Float16 f16x8 __attribute__((ext_vector_type(8)));
typedef __fp16 fp16x2 __attribute__((ext_vector_type(2)));
typedef float f32x16 __attribute__((ext_vector_type(16)));

// ---------------------------------------------------------------------------
// Kernel 1: three causal (reflect-padded) convs. R6 structure (direct taps,
// no input staging) + 2-way oc split: grid = 768 = 3 parts x 2 halves x 128
// position blocks (exactly 3 blocks/CU, no tail imbalance).
// part 0: qe = conv(q, wq) * QSCALE -> [b][s][8] f16  (exp2-domain scale)
// part 1: ke = conv(v, wk)          -> [b][s][8] f16  (swapped wiring!)
// part 2: ve = conv(k, wv)          -> vt [b][n][s] f16 (TRANSPOSED)
// ---------------------------------------------------------------------------
__global__ __launch_bounds__(256) void conv_embed_kernel(
    const float* __restrict__ q, const float* __restrict__ k,
    const float* __restrict__ v, const float* __restrict__ wq,
    const float* __restrict__ wk, const float* __restrict__ wv,
    f16* __restrict__ qe, f16* __restrict__ ke, f16* __restrict__ vt)
{
    __shared__ float wsm[80];

    int tid  = threadIdx.x;
    int blk  = blockIdx.x & 127;
    int grp  = blockIdx.x >> 7;    // 0..5
    int part = grp >> 1;           // 0,1,2
    int oh   = grp & 1;            // oc half

    const float* in; const float* wsrc;
    if (part == 0)      { in = q; wsrc = wq; }
    else if (part == 1) { in = v; wsrc = wk; }   // ke = conv(v, wk)
    else                { in = k; wsrc = wv; }   // ve = conv(k, wv)

    if (tid < 80) wsm[tid] = wsrc[oh * 80 + tid];
    __syncthreads();

    int gid = blk * 256 + tid;     // b*S + s
    int s = gid & (S - 1);
    int b = gid >> 11;

    float x[CIN][KW];
#pragma unroll
    for (int c = 0; c < CIN; ++c) {
        const float* ip = in + ((size_t)(b * CIN + c) << 11);
#pragma unroll
        for (int i = 0; i < KW; ++i) {
            int idx = s + i - 4;
            idx = idx < 0 ? -idx : idx;   // reflect pad
            x[c][i] = ip[idx];
        }
    }

    float o[4];
#pragma unroll
    for (int oo = 0; oo < 4; ++oo) {
        float a = 0.f;
#pragma unroll
        for (int c = 0; c < CIN; ++c)
#pragma unroll
            for (int i = 0; i < KW; ++i)
                a += x[c][i] * wsm[oo * 20 + c * 5 + i];
        o[oo] = a;
    }

    const float QSCALE = 0.35355339059327373f * 1.4426950408889634f; // (1/sqrt8)*log2e

    if (part == 2) {
#pragma unroll
        for (int oo = 0; oo < 4; ++oo)
            vt[((size_t)(b * COUT + oh * 4 + oo) << 11) + s] = (f16)o[oo];
    } else {
        float sc = (part == 0) ? QSCALE : 1.0f;
        f16x4 r;
#pragma unroll
        for (int oo = 0; oo < 4; ++oo) r[oo] = (f16)(o[oo] * sc);
        f16* dst = ((part == 0) ? qe : ke) + ((size_t)gid << 3) + oh * 4;
        *(f16x4*)dst = r;
    }
}

// ---------------------------------------------------------------------------
// Kernel 2: flash attention via v_mfma_f32_32x32x16_f16 — exact R6 inner
// loop (predicated V loads; no register prefetch), but 8 waves per block
// (512 threads), each wave owning 256 kv -> 8192 waves = 100% occupancy.
//
// SPLIT-K fragment layout (gfx950 = two stacked legacy 32x32x8 fragments):
//   A[m][k], B[k][n]: lane l elem j <-> k = (l>>5)*4 + (j&3) + 8*(j>>2)
//   C/D: col = lane&31, row = (r&3) + 8*(r>>2) + 4*(lane>>5)
// QK^T swapped: C[kv][q] = mfma(A=K, B=Q^T); p = exp2(C) feeds PV's B
// fragment DIRECTLY. PV: C[n][q] += mfma(A=V^T, B=P) x2; lane row n==8 uses
// constant-1 A-frag -> row 8 accumulates denominator l.
// ---------------------------------------------------------------------------
#define QT 32
#define NWAVE 8
#define KVC (S / NWAVE)   // 256 kv per wave

__global__ __launch_bounds__(512, 8) void attn_mfma_kernel(
    const f16* __restrict__ qe, const f16* __restrict__ ke,
    const f16* __restrict__ vt, const float* __restrict__ w_out,
    const float* __restrict__ b_out, float* __restrict__ out)
{
    __shared__ float red[NWAVE][9][QT];

    int tid  = threadIdx.x;
    int w    = tid >> 6;
    int lane = tid & 63;
    int hi   = lane >> 5;
    int ln   = lane & 31;

    int b  = blockIdx.x >> 6;      // 64 q-tiles per batch
    int q0 = (blockIdx.x & 63) * QT;

    // Q fragment (B operand): elems 0..3 = Q[q0+ln][4*hi .. 4*hi+3]
    f16x4 qh = *(const f16x4*)(qe + ((size_t)(b * S + q0 + ln) << 3) + hi * 4);
    f16x8 qb = {qh[0], qh[1], qh[2], qh[3], (f16)0, (f16)0, (f16)0, (f16)0};

    const f16* vrow = vt + ((size_t)(b * COUT + ln) << 11);  // deref'd only if ln<8

    f32x16 oacc = {};              // C[n][q]; row n=8 accumulates l

    int kv0 = w * KVC;
    for (int it = 0; it < KVC / 32; ++it, kv0 += 32) {
        // ---- QK^T ----
        f16x4 kh = *(const f16x4*)(ke + ((size_t)(b * S + kv0 + ln) << 3) + hi * 4);
        f16x8 ka = {kh[0], kh[1], kh[2], kh[3], (f16)0, (f16)0, (f16)0, (f16)0};
        f32x16 sc = {};
        sc = __builtin_amdgcn_mfma_f32_32x32x16_f16(ka, qb, sc, 0, 0, 0);

        // ---- exp2 (pre-scaled scores; no max tracking) ----
        float p[16];
#pragma unroll
        for (int r = 0; r < 16; ++r) p[r] = __builtin_amdgcn_exp2f(sc[r]);

        // ---- pack to f16; owned C-rows == needed B-frag k-indices ----
        union { f16x8 v; fp16x2 h[4]; } p1, p2;
#pragma unroll
        for (int i = 0; i < 4; ++i) {
            p1.h[i] = __builtin_amdgcn_cvt_pkrtz(p[2 * i],     p[2 * i + 1]);
            p2.h[i] = __builtin_amdgcn_cvt_pkrtz(p[8 + 2 * i], p[8 + 2 * i + 1]);
        }

        // ---- V^T A-fragments (predicated: masked lanes issue no loads) ----
        f16x8 va1, va2;
        if (ln < COUT) {
            const f16* vr = vrow + kv0;
            f16x4 a0 = *(const f16x4*)(vr + hi * 4);
            f16x4 a1 = *(const f16x4*)(vr + 8 + hi * 4);
            f16x4 a2 = *(const f16x4*)(vr + 16 + hi * 4);
            f16x4 a3 = *(const f16x4*)(vr + 24 + hi * 4);
            va1 = (f16x8){a0[0], a0[1], a0[2], a0[3], a1[0], a1[1], a1[2], a1[3]};
            va2 = (f16x8){a2[0], a2[1], a2[2], a2[3], a3[0], a3[1], a3[2], a3[3]};
        } else if (ln == COUT) {
            f16 one = (f16)1.0f;
            va1 = (f16x8){one, one, one, one, one, one, one, one};
            va2 = va1;
        } else {
            va1 = (f16x8){};
            va2 = (f16x8){};
        }

        oacc = __builtin_amdgcn_mfma_f32_32x32x16_f16(va1, p1.v, oacc, 0, 0, 0);
        oacc = __builtin_amdgcn_mfma_f32_32x32x16_f16(va2, p2.v, oacc, 0, 0, 0);
    }

    // ---- epilogue: dump useful C rows (n<9) to LDS ----
#pragma unroll
    for (int r = 0; r < 16; ++r) {
        int n = (r & 3) + 8 * (r >> 2) + 4 * hi;
        if (n < 9) red[w][n][ln] = oacc[r];
    }
    __syncthreads();

    // Reduce the 8 kv-chunk waves: 9 rows x 32 q = 288 items (512 threads).
    if (tid < 9 * QT) {
        int n = tid >> 5, qq = tid & 31;
        float a = red[0][n][qq];
#pragma unroll
        for (int ww = 1; ww < NWAVE; ++ww) a += red[ww][n][qq];
        red[0][n][qq] = a;
    }
    __syncthreads();

    if (tid < 256) {
        int cp = tid >> 5, qq = tid & 31;   // 8 channels x 32 q
        float inv = 1.0f / red[0][8][qq];
        float y = b_out[cp];
#pragma unroll
        for (int c = 0; c < 8; ++c) y += w_out[cp * 8 + c] * red[0][c][qq] * inv;
        out[(((size_t)(b * COUT + cp)) << 11) + q0 + qq] = y;
    }
}

// ---------------------------------------------------------------------------
extern "C" void kernel_launch(void* const* d_in, const int* in_sizes, int n_in,
                              void* d_out, int out_size, void* d_ws, size_t ws_size,
                              hipStream_t stream)
{
    const float* q     = (const float*)d_in[0];
    const float* k     = (const float*)d_in[1];
    const float* v     = (const float*)d_in[2];
    const float* wq    = (const float*)d_in[3];
    const float* wk    = (const float*)d_in[4];
    const float* wv    = (const float*)d_in[5];
    const float* w_out = (const float*)d_in[6];
    const float* b_out = (const float*)d_in[7];
    float* out = (float*)d_out;

    f16* qe = (f16*)d_ws;                        // [B][S][8]
    f16* ke = qe + (size_t)BS * COUT;            // [B][S][8]
    f16* vt = ke + (size_t)BS * COUT;            // [B][8][S]

    conv_embed_kernel<<<768, 256, 0, stream>>>(q, k, v, wq, wk, wv, qe, ke, vt);
    attn_mfma_kernel<<<B * (S / QT), 512, 0, stream>>>(qe, ke, vt, w_out, b_out, out);
}

// Round 11
// 20.096 us; speedup vs baseline: 6.9638x; 1.3290x over previous
//
#include <hip/hip_runtime.h>

#define B 16
#define CIN 4
#define COUT 8
#define KW 5
#define S 2048
#define BS (B * S)

typedef _Float16 f16;
typedef _Float16 f16x4 __attribute__((ext_vector_type(4)));
typedef _Float16 f16x8 __attribute__((ext_vector_type(8)));
typedef __fp16 fp16x2 __attribute__((ext_vector_type(2)));
typedef float f32x16 __attribute__((ext_vector_type(16)));

// V^T fragment ordering within a 32-kv tile (A-operand of PV MFMA):
// off(k) = hi(k)*16 + whichva(k)*8 + (k&3) + sub(k)*4
//   hi = (k>>2)&1, whichva = (k>>4)&1, sub = (k>>3)&1
__device__ __forceinline__ int vfrag_off(int k) {
    return (((k >> 2) & 1) << 4) | (((k >> 4) & 1) << 3) | (k & 3) | (((k >> 3) & 1) << 2);
}

// ---------------------------------------------------------------------------
// Kernel 1: three causal (reflect-padded) convs; grid = 768 = 3 parts x
// 2 oc-halves x 128 position blocks (3 blocks/CU).
// part 0: qe = conv(q, wq) * QSCALE -> [b][s][8] f16   (exp2-domain scale)
// part 1: ke = conv(v, wk)          -> [b][s][8] f16   (swapped wiring!)
// part 2: ve = conv(k, wv)          -> vt2 [b][tile][n][frag-order] f16,
//          with row n=8 = 1.0 (ones row -> softmax denominator via PV MFMA).
// ---------------------------------------------------------------------------
__global__ __launch_bounds__(256) void conv_embed_kernel(
    const float* __restrict__ q, const float* __restrict__ k,
    const float* __restrict__ v, const float* __restrict__ wq,
    const float* __restrict__ wk, const float* __restrict__ wv,
    f16* __restrict__ qe, f16* __restrict__ ke, f16* __restrict__ vt2)
{
    __shared__ float wsm[80];

    int tid  = threadIdx.x;
    int blk  = blockIdx.x & 127;
    int grp  = blockIdx.x >> 7;    // 0..5
    int part = grp >> 1;           // 0,1,2
    int oh   = grp & 1;            // oc half

    const float* in; const float* wsrc;
    if (part == 0)      { in = q; wsrc = wq; }
    else if (part == 1) { in = v; wsrc = wk; }   // ke = conv(v, wk)
    else                { in = k; wsrc = wv; }   // ve = conv(k, wv)

    if (tid < 80) wsm[tid] = wsrc[oh * 80 + tid];
    __syncthreads();

    int gid = blk * 256 + tid;     // b*S + s
    int s = gid & (S - 1);
    int b = gid >> 11;

    float x[CIN][KW];
#pragma unroll
    for (int c = 0; c < CIN; ++c) {
        const float* ip = in + ((size_t)(b * CIN + c) << 11);
#pragma unroll
        for (int i = 0; i < KW; ++i) {
            int idx = s + i - 4;
            idx = idx < 0 ? -idx : idx;   // reflect pad
            x[c][i] = ip[idx];
        }
    }

    float o[4];
#pragma unroll
    for (int oo = 0; oo < 4; ++oo) {
        float a = 0.f;
#pragma unroll
        for (int c = 0; c < CIN; ++c)
#pragma unroll
            for (int i = 0; i < KW; ++i)
                a += x[c][i] * wsm[oo * 20 + c * 5 + i];
        o[oo] = a;
    }

    const float QSCALE = 0.35355339059327373f * 1.4426950408889634f; // (1/sqrt8)*log2e

    if (part == 2) {
        int t   = s >> 5;
        int off = vfrag_off(s & 31);
        size_t base = (size_t)(b * 64 + t) * 9;
#pragma unroll
        for (int oo = 0; oo < 4; ++oo)
            vt2[((base + oh * 4 + oo) << 5) + off] = (f16)o[oo];
        if (oh == 0)                                   // ones row (n = 8)
            vt2[((base + 8) << 5) + off] = (f16)1.0f;
    } else {
        float sc = (part == 0) ? QSCALE : 1.0f;
        f16x4 r;
#pragma unroll
        for (int oo = 0; oo < 4; ++oo) r[oo] = (f16)(o[oo] * sc);
        f16* dst = ((part == 0) ? qe : ke) + ((size_t)gid << 3) + oh * 4;
        *(f16x4*)dst = r;
    }
}

// ---------------------------------------------------------------------------
// Kernel 2: flash attention via v_mfma_f32_32x32x16_f16, instruction-trimmed:
// persistent-zero C-in (no per-iter acc zeroing), preserved-zero ka upper
// half, fragment-ordered V loads (2x f16x8, no assembly), pointer bumps,
// exp2 fused into cvt_pk operands, setprio around PV MFMAs.
//
// SPLIT-K fragment layout (gfx950 = two stacked legacy 32x32x8 fragments):
//   A[m][k], B[k][n]: lane l elem j <-> k = (l>>5)*4 + (j&3) + 8*(j>>2)
//   C/D: col = lane&31, row = (r&3) + 8*(r>>2) + 4*(lane>>5)
// QK^T swapped: C[kv][q] = mfma(A=K, B=Q^T); p = exp2(C) feeds PV's B
// fragment DIRECTLY. PV: C[n][q] += mfma(A=V^T, B=P) x2; row n==8 (ones row
// in vt2) accumulates the softmax denominator l.
// ---------------------------------------------------------------------------
#define QT 32
#define NWAVE 8
#define KVC (S / NWAVE)   // 256 kv per wave

__global__ __launch_bounds__(512, 8) void attn_mfma_kernel(
    const f16* __restrict__ qe, const f16* __restrict__ ke,
    const f16* __restrict__ vt2, const float* __restrict__ w_out,
    const float* __restrict__ b_out, float* __restrict__ out)
{
    __shared__ float red[NWAVE][9][QT];

    int tid  = threadIdx.x;
    int w    = tid >> 6;
    int lane = tid & 63;
    int hi   = lane >> 5;
    int ln   = lane & 31;

    int b  = blockIdx.x >> 6;      // 64 q-tiles per batch
    int q0 = (blockIdx.x & 63) * QT;

    // Q fragment (B operand), hoisted: elems 0..3 = Q[q0+ln][4*hi..4*hi+3]
    union { f16x8 v8; f16x4 v4[2]; } qbu;
    qbu.v8 = (f16x8){};
    qbu.v4[0] = *(const f16x4*)(qe + ((size_t)(b * S + q0 + ln) << 3) + hi * 4);

    // K fragment holder: upper half stays zero across the whole loop.
    union { f16x8 v8; f16x4 v4[2]; } kau;
    kau.v8 = (f16x8){};

    const f32x16 zero16 = {};
    f32x16 oacc = {};              // C[n][q]; row n=8 accumulates l

    const f16* kptr = ke + ((size_t)(b * S + w * KVC + ln) << 3) + hi * 4;
    const f16* vptr = vt2 + (((size_t)(b * 64 + w * (KVC / 32)) * 9 + ln) << 5) + hi * 16;

    for (int it = 0; it < KVC / 32; ++it) {
        // ---- QK^T (C-in = persistent zero bank) ----
        kau.v4[0] = *(const f16x4*)kptr;
        kptr += 32 * 8;
        f32x16 sc = __builtin_amdgcn_mfma_f32_32x32x16_f16(kau.v8, qbu.v8, zero16, 0, 0, 0);

        // ---- exp2 fused into f16 pack (owned C-rows == needed B-frag k) ----
        union { f16x8 v; fp16x2 h[4]; } p1, p2;
#pragma unroll
        for (int i = 0; i < 4; ++i) {
            p1.h[i] = __builtin_amdgcn_cvt_pkrtz(__builtin_amdgcn_exp2f(sc[2 * i]),
                                                 __builtin_amdgcn_exp2f(sc[2 * i + 1]));
            p2.h[i] = __builtin_amdgcn_cvt_pkrtz(__builtin_amdgcn_exp2f(sc[8 + 2 * i]),
                                                 __builtin_amdgcn_exp2f(sc[8 + 2 * i + 1]));
        }

        // ---- V^T A-fragments: direct fragment-ordered loads (rows 0..8) ----
        f16x8 va1, va2;
        if (ln < 9) {
            va1 = *(const f16x8*)(vptr);
            va2 = *(const f16x8*)(vptr + 8);
        } else {
            va1 = (f16x8){};
            va2 = (f16x8){};
        }
        vptr += 9 * 32;

        __builtin_amdgcn_s_setprio(1);
        oacc = __builtin_amdgcn_mfma_f32_32x32x16_f16(va1, p1.v, oacc, 0, 0, 0);
        oacc = __builtin_amdgcn_mfma_f32_32x32x16_f16(va2, p2.v, oacc, 0, 0, 0);
        __builtin_amdgcn_s_setprio(0);
    }

    // ---- epilogue: dump useful C rows (n<9) to LDS ----
#pragma unroll
    for (int r = 0; r < 16; ++r) {
        int n = (r & 3) + 8 * (r >> 2) + 4 * hi;
        if (n < 9) red[w][n][ln] = oacc[r];
    }
    __syncthreads();

    // Reduce the 8 kv-chunk waves: 9 rows x 32 q = 288 items (512 threads).
    if (tid < 9 * QT) {
        int n = tid >> 5, qq = tid & 31;
        float a = red[0][n][qq];
#pragma unroll
        for (int ww = 1; ww < NWAVE; ++ww) a += red[ww][n][qq];
        red[0][n][qq] = a;
    }
    __syncthreads();

    if (tid < 256) {
        int cp = tid >> 5, qq = tid & 31;   // 8 channels x 32 q
        float inv = 1.0f / red[0][8][qq];
        float y = b_out[cp];
#pragma unroll
        for (int c = 0; c < 8; ++c) y += w_out[cp * 8 + c] * red[0][c][qq] * inv;
        out[(((size_t)(b * COUT + cp)) << 11) + q0 + qq] = y;
    }
}

// ---------------------------------------------------------------------------
extern "C" void kernel_launch(void* const* d_in, const int* in_sizes, int n_in,
                              void* d_out, int out_size, void* d_ws, size_t ws_size,
                              hipStream_t stream)
{
    const float* q     = (const float*)d_in[0];
    const float* k     = (const float*)d_in[1];
    const float* v     = (const float*)d_in[2];
    const float* wq    = (const float*)d_in[3];
    const float* wk    = (const float*)d_in[4];
    const float* wv    = (const float*)d_in[5];
    const float* w_out = (const float*)d_in[6];
    const float* b_out = (const float*)d_in[7];
    float* out = (float*)d_out;

    f16* qe  = (f16*)d_ws;                       // [B][S][8]
    f16* ke  = qe + (size_t)BS * COUT;           // [B][S][8]
    f16* vt2 = ke + (size_t)BS * COUT;           // [B][64][9][32] frag-ordered

    conv_embed_kernel<<<768, 256, 0, stream>>>(q, k, v, wq, wk, wv, qe, ke, vt2);
    attn_mfma_kernel<<<B * (S / QT), 512, 0, stream>>>(qe, ke, vt2, w_out, b_out, out);
}

// Round 12
// 20.025 us; speedup vs baseline: 6.9884x; 1.0035x over previous
//
#include <hip/hip_runtime.h>

#define B 16
#define CIN 4
#define COUT 8
#define KW 5
#define S 2048
#define BS (B * S)

typedef _Float16 f16;
typedef _Float16 f16x4 __attribute__((ext_vector_type(4)));
typedef _Float16 f16x8 __attribute__((ext_vector_type(8)));
typedef __fp16 fp16x2 __attribute__((ext_vector_type(2)));
typedef float f32x16 __attribute__((ext_vector_type(16)));

// V^T fragment ordering within a 32-kv tile (A-operand of PV MFMA):
// off(k) = hi(k)*16 + whichva(k)*8 + (k&3) + sub(k)*4
__device__ __forceinline__ int vfrag_off(int k) {
    return (((k >> 2) & 1) << 4) | (((k >> 4) & 1) << 3) | (k & 3) | (((k >> 3) & 1) << 2);
}

// ---------------------------------------------------------------------------
// Kernel 1: three causal (reflect-padded) convs; grid = 768 = 3 parts x
// 2 oc-halves x 128 position blocks (3 blocks/CU).  (unchanged from R11)
// part 0: qe = conv(q, wq) * QSCALE -> [b][s][8] f16   (exp2-domain scale)
// part 1: ke = conv(v, wk)          -> [b][s][8] f16   (swapped wiring!)
// part 2: ve = conv(k, wv)          -> vt2 [b][tile][n][frag-order] f16,
//          with row n=8 = 1.0 (ones row -> softmax denominator via PV MFMA).
// ---------------------------------------------------------------------------
__global__ __launch_bounds__(256) void conv_embed_kernel(
    const float* __restrict__ q, const float* __restrict__ k,
    const float* __restrict__ v, const float* __restrict__ wq,
    const float* __restrict__ wk, const float* __restrict__ wv,
    f16* __restrict__ qe, f16* __restrict__ ke, f16* __restrict__ vt2)
{
    __shared__ float wsm[80];

    int tid  = threadIdx.x;
    int blk  = blockIdx.x & 127;
    int grp  = blockIdx.x >> 7;    // 0..5
    int part = grp >> 1;           // 0,1,2
    int oh   = grp & 1;            // oc half

    const float* in; const float* wsrc;
    if (part == 0)      { in = q; wsrc = wq; }
    else if (part == 1) { in = v; wsrc = wk; }   // ke = conv(v, wk)
    else                { in = k; wsrc = wv; }   // ve = conv(k, wv)

    if (tid < 80) wsm[tid] = wsrc[oh * 80 + tid];
    __syncthreads();

    int gid = blk * 256 + tid;     // b*S + s
    int s = gid & (S - 1);
    int b = gid >> 11;

    float x[CIN][KW];
#pragma unroll
    for (int c = 0; c < CIN; ++c) {
        const float* ip = in + ((size_t)(b * CIN + c) << 11);
#pragma unroll
        for (int i = 0; i < KW; ++i) {
            int idx = s + i - 4;
            idx = idx < 0 ? -idx : idx;   // reflect pad
            x[c][i] = ip[idx];
        }
    }

    float o[4];
#pragma unroll
    for (int oo = 0; oo < 4; ++oo) {
        float a = 0.f;
#pragma unroll
        for (int c = 0; c < CIN; ++c)
#pragma unroll
            for (int i = 0; i < KW; ++i)
                a += x[c][i] * wsm[oo * 20 + c * 5 + i];
        o[oo] = a;
    }

    const float QSCALE = 0.35355339059327373f * 1.4426950408889634f; // (1/sqrt8)*log2e

    if (part == 2) {
        int t   = s >> 5;
        int off = vfrag_off(s & 31);
        size_t base = (size_t)(b * 64 + t) * 9;
#pragma unroll
        for (int oo = 0; oo < 4; ++oo)
            vt2[((base + oh * 4 + oo) << 5) + off] = (f16)o[oo];
        if (oh == 0)                                   // ones row (n = 8)
            vt2[((base + 8) << 5) + off] = (f16)1.0f;
    } else {
        float sc = (part == 0) ? QSCALE : 1.0f;
        f16x4 r;
#pragma unroll
        for (int oo = 0; oo < 4; ++oo) r[oo] = (f16)(o[oo] * sc);
        f16* dst = ((part == 0) ? qe : ke) + ((size_t)gid << 3) + oh * 4;
        *(f16x4*)dst = r;
    }
}

// ---------------------------------------------------------------------------
// Kernel 2: flash attention. R12 changes: __launch_bounds__(512,4) frees the
// register allocator (128 VGPR: load hoisting/pipelining possible, no spill
// risk — R10 proved 4 waves/SIMD == 8 waves/SIMD here); QK^T uses the K=8
// MFMA (exact d=8 fit, no zero padding); setprio removed (suspect wave
// serializer under multi-wave); full unroll of the kv loop.
//
// SPLIT-K fragment layout:
//   32x32x8  A/B: lane l elem j <-> k = (l>>5)*4 + j
//   32x32x16 A/B: lane l elem j <-> k = (l>>5)*4 + (j&3) + 8*(j>>2)
//   C/D (both): col = lane&31, row = (r&3) + 8*(r>>2) + 4*(lane>>5)
// QK^T swapped: C[kv][q] = mfma(A=K, B=Q^T); p = exp2(C) feeds PV's B
// fragment DIRECTLY. PV: C[n][q] += mfma(A=V^T, B=P) x2; row n==8 (ones row
// in vt2) accumulates the softmax denominator l.
// ---------------------------------------------------------------------------
#define QT 32
#define NWAVE 8
#define KVC (S / NWAVE)   // 256 kv per wave

#if __has_builtin(__builtin_amdgcn_mfma_f32_32x32x8f16)
#define HAVE_K8 1
#else
#define HAVE_K8 0
#endif

__global__ __launch_bounds__(512, 4) void attn_mfma_kernel(
    const f16* __restrict__ qe, const f16* __restrict__ ke,
    const f16* __restrict__ vt2, const float* __restrict__ w_out,
    const float* __restrict__ b_out, float* __restrict__ out)
{
    __shared__ float red[NWAVE][9][QT];

    int tid  = threadIdx.x;
    int w    = tid >> 6;
    int lane = tid & 63;
    int hi   = lane >> 5;
    int ln   = lane & 31;

    int b  = blockIdx.x >> 6;      // 64 q-tiles per batch
    int q0 = (blockIdx.x & 63) * QT;

    // Q fragment (B operand): elems 0..3 = Q[q0+ln][4*hi..4*hi+3]
    f16x4 qb4 = *(const f16x4*)(qe + ((size_t)(b * S + q0 + ln) << 3) + hi * 4);
#if !HAVE_K8
    f16x8 qb8 = {qb4[0], qb4[1], qb4[2], qb4[3], (f16)0, (f16)0, (f16)0, (f16)0};
#endif

    const f32x16 zero16 = {};
    f32x16 oacc = {};              // C[n][q]; row n=8 accumulates l

    const f16* kptr = ke + ((size_t)(b * S + w * KVC + ln) << 3) + hi * 4;
    const f16* vptr = vt2 + (((size_t)(b * 64 + w * (KVC / 32)) * 9 + ln) << 5) + hi * 16;

#pragma unroll
    for (int it = 0; it < KVC / 32; ++it) {
        // ---- QK^T: K=8 MFMA (exact d=8), C-in = persistent zero ----
        f16x4 kh = *(const f16x4*)kptr;
        kptr += 32 * 8;
#if HAVE_K8
        f32x16 sc = __builtin_amdgcn_mfma_f32_32x32x8f16(kh, qb4, zero16, 0, 0, 0);
#else
        f16x8 ka = {kh[0], kh[1], kh[2], kh[3], (f16)0, (f16)0, (f16)0, (f16)0};
        f32x16 sc = __builtin_amdgcn_mfma_f32_32x32x16_f16(ka, qb8, zero16, 0, 0, 0);
#endif

        // ---- exp2 fused into f16 pack (owned C-rows == needed B-frag k) ----
        union { f16x8 v; fp16x2 h[4]; } p1, p2;
#pragma unroll
        for (int i = 0; i < 4; ++i) {
            p1.h[i] = __builtin_amdgcn_cvt_pkrtz(__builtin_amdgcn_exp2f(sc[2 * i]),
                                                 __builtin_amdgcn_exp2f(sc[2 * i + 1]));
            p2.h[i] = __builtin_amdgcn_cvt_pkrtz(__builtin_amdgcn_exp2f(sc[8 + 2 * i]),
                                                 __builtin_amdgcn_exp2f(sc[8 + 2 * i + 1]));
        }

        // ---- V^T A-fragments: direct fragment-ordered loads (rows 0..8) ----
        f16x8 va1, va2;
        if (ln < 9) {
            va1 = *(const f16x8*)(vptr);
            va2 = *(const f16x8*)(vptr + 8);
        } else {
            va1 = (f16x8){};
            va2 = (f16x8){};
        }
        vptr += 9 * 32;

        oacc = __builtin_amdgcn_mfma_f32_32x32x16_f16(va1, p1.v, oacc, 0, 0, 0);
        oacc = __builtin_amdgcn_mfma_f32_32x32x16_f16(va2, p2.v, oacc, 0, 0, 0);
    }

    // ---- epilogue: dump useful C rows (n<9) to LDS ----
#pragma unroll
    for (int r = 0; r < 16; ++r) {
        int n = (r & 3) + 8 * (r >> 2) + 4 * hi;
        if (n < 9) red[w][n][ln] = oacc[r];
    }
    __syncthreads();

    // Reduce the 8 kv-chunk waves: 9 rows x 32 q = 288 items (512 threads).
    if (tid < 9 * QT) {
        int n = tid >> 5, qq = tid & 31;
        float a = red[0][n][qq];
#pragma unroll
        for (int ww = 1; ww < NWAVE; ++ww) a += red[ww][n][qq];
        red[0][n][qq] = a;
    }
    __syncthreads();

    if (tid < 256) {
        int cp = tid >> 5, qq = tid & 31;   // 8 channels x 32 q
        float inv = 1.0f / red[0][8][qq];
        float y = b_out[cp];
#pragma unroll
        for (int c = 0; c < 8; ++c) y += w_out[cp * 8 + c] * red[0][c][qq] * inv;
        out[(((size_t)(b * COUT + cp)) << 11) + q0 + qq] = y;
    }
}

// ---------------------------------------------------------------------------
extern "C" void kernel_launch(void* const* d_in, const int* in_sizes, int n_in,
                              void* d_out, int out_size, void* d_ws, size_t ws_size,
                              hipStream_t stream)
{
    const float* q     = (const float*)d_in[0];
    const float* k     = (const float*)d_in[1];
    const float* v     = (const float*)d_in[2];
    const float* wq    = (const float*)d_in[3];
    const float* wk    = (const float*)d_in[4];
    const float* wv    = (const float*)d_in[5];
    const float* w_out = (const float*)d_in[6];
    const float* b_out = (const float*)d_in[7];
    float* out = (float*)d_out;

    f16* qe  = (f16*)d_ws;                       // [B][S][8]
    f16* ke  = qe + (size_t)BS * COUT;           // [B][S][8]
    f16* vt2 = ke + (size_t)BS * COUT;           // [B][64][9][32] frag-ordered

    conv_embed_kernel<<<768, 256, 0, stream>>>(q, k, v, wq, wk, wv, qe, ke, vt2);
    attn_mfma_kernel<<<B * (S / QT), 512, 0, stream>>>(qe, ke, vt2, w_out, b_out, out);
}